// Round 1
// baseline (425.693 us; speedup 1.0000x reference)
//
#include <hip/hip_runtime.h>
#include <hip/hip_bf16.h>

// CrossCovarianceAttn (XCiT channel attention), MI355X gfx950.
// Pipeline:
//   K0: transpose+cast Wqkv -> WqkvT bf16 [2304][768]
//   K1: GEMM1 qkvB = bf16(x @ Wqkv + bqkv)   [32768][2304] bf16
//   K2: per (b,h,split): 128x128 Gram of [q|k] over n-chunk (MFMA), partials fp32
//   K3: reduce partials -> norms + softmax -> attn [48][64][64] fp32
//   K4: WcombT[b][j][h*64+e] = sum_d attn[b,h,d,e] * Wproj[h*64+d][j]  (bf16)
//   K5: GEMM2 out = V @ Wcomb[b] + bproj  (fp32 out)

using short8 = __attribute__((ext_vector_type(8))) short;
using f32x4  = __attribute__((ext_vector_type(4))) float;

#define B_   4
#define N_   8192
#define C_   768
#define H_   12
#define HD_  64
#define N1_  (3*C_)      // 2304
#define MTOT (B_*N_)     // 32768
#define SPLITS 8
#define NCHUNK (N_/SPLITS)  // 1024

__device__ __forceinline__ unsigned short f2b(float f){
  union { float f; unsigned u; } v; v.f = f;
  unsigned u = v.u;
  u += 0x7fffu + ((u >> 16) & 1u);   // RNE
  return (unsigned short)(u >> 16);
}

// ---------------- K0: Wqkv [768][2304] fp32 -> WqkvT [2304][768] bf16 ----
__global__ __launch_bounds__(256)
void transpose_w(const float* __restrict__ W, unsigned short* __restrict__ Wt,
                 int rows, int cols)
{
  __shared__ float tile[32][33];
  const int ctiles = cols / 32;
  const int bx = blockIdx.x % ctiles;   // col tile
  const int by = blockIdx.x / ctiles;   // row tile
  const int t = threadIdx.x;
  const int c = t & 31;
  #pragma unroll
  for (int i = 0; i < 4; ++i){
    int r = i*8 + (t >> 5);
    tile[r][c] = W[(long)(by*32 + r)*cols + bx*32 + c];
  }
  __syncthreads();
  #pragma unroll
  for (int i = 0; i < 4; ++i){
    int r = i*8 + (t >> 5);             // output row within tile (= original col)
    Wt[(long)(bx*32 + r)*rows + by*32 + c] = f2b(tile[c][r]);
  }
}

// ---------------- GEMM (bf16 MFMA, B pre-transposed [N][K]) --------------
// A_F32: A is fp32 (convert inline) else bf16. OUT_B16: bf16 out else fp32.
// B_PER_B: B matrix selected per batch (row block / N_).
template<int A_F32, int OUT_B16, int B_PER_B>
__global__ __launch_bounds__(256)
void gemm_bt(const void* __restrict__ Ap, int lda, int a_off,
             const unsigned short* __restrict__ Bt,
             const float* __restrict__ bias,
             void* __restrict__ Outp, int ldo,
             int Mtiles, int K)
{
  __shared__ unsigned short As[128][72];  // pad 72 elems (144B) -> conflict-free b128
  __shared__ unsigned short Bs[128][72];
  const int t = threadIdx.x;
  const int lane = t & 63, w = t >> 6, wr = w >> 1, wc = w & 1;
  const int mt = blockIdx.x % Mtiles;
  const int nt = blockIdx.x / Mtiles;
  const long m0 = (long)mt * 128;
  const int  n0 = nt * 128;
  const unsigned short* B0 = Bt + (B_PER_B ? (long)(m0 / N_) * C_ * C_ : 0);
  f32x4 acc[4][4] = {};
  const int ksteps = K / 64;
  for (int ks = 0; ks < ksteps; ++ks){
    const int k0 = ks * 64;
    __syncthreads();
    if (A_F32){
      const float* A = (const float*)Ap;
      #pragma unroll
      for (int i = 0; i < 8; ++i){
        int idx = i*256 + t, r = idx >> 4, k = (idx & 15) * 4;
        const f32x4 v = *(const f32x4*)(A + (m0 + r)*(long)lda + a_off + k0 + k);
        unsigned lo = (unsigned)f2b(v[0]) | ((unsigned)f2b(v[1]) << 16);
        unsigned hi = (unsigned)f2b(v[2]) | ((unsigned)f2b(v[3]) << 16);
        *(uint2*)&As[r][k] = make_uint2(lo, hi);
      }
    } else {
      const unsigned short* A = (const unsigned short*)Ap;
      #pragma unroll
      for (int i = 0; i < 4; ++i){
        int idx = i*256 + t, r = idx >> 3, k = (idx & 7) * 8;
        *(uint4*)&As[r][k] = *(const uint4*)(A + (m0 + r)*(long)lda + a_off + k0 + k);
      }
    }
    #pragma unroll
    for (int i = 0; i < 4; ++i){
      int idx = i*256 + t, r = idx >> 3, k = (idx & 7) * 8;
      *(uint4*)&Bs[r][k] = *(const uint4*)(B0 + (long)(n0 + r)*K + k0 + k);
    }
    __syncthreads();
    #pragma unroll
    for (int kk = 0; kk < 2; ++kk){
      const int koff = kk*32 + (lane >> 4) * 8;
      short8 a[4], bb[4];
      #pragma unroll
      for (int m = 0; m < 4; ++m)
        a[m] = *(const short8*)&As[wr*64 + m*16 + (lane & 15)][koff];
      #pragma unroll
      for (int n = 0; n < 4; ++n)
        bb[n] = *(const short8*)&Bs[wc*64 + n*16 + (lane & 15)][koff];
      #pragma unroll
      for (int m = 0; m < 4; ++m)
        #pragma unroll
        for (int n = 0; n < 4; ++n)
          acc[m][n] = __builtin_amdgcn_mfma_f32_16x16x32_bf16(a[m], bb[n], acc[m][n], 0, 0, 0);
    }
  }
  const int rl = (lane >> 4) * 4, cl = lane & 15;
  #pragma unroll
  for (int m = 0; m < 4; ++m){
    const long gr = m0 + wr*64 + m*16 + rl;
    #pragma unroll
    for (int n = 0; n < 4; ++n){
      const int gc = n0 + wc*64 + n*16 + cl;
      const float bv = bias[gc];
      #pragma unroll
      for (int j = 0; j < 4; ++j){
        float v = acc[m][n][j] + bv;
        if (OUT_B16) ((unsigned short*)Outp)[(gr + j)*(long)ldo + gc] = f2b(v);
        else         ((float*)Outp)[(gr + j)*(long)ldo + gc] = v;
      }
    }
  }
}

// ---------------- K2: per (b,h,split) 128x128 Gram of stacked [q|k] ------
__global__ __launch_bounds__(256)
void gram_qk(const unsigned short* __restrict__ qkv, float* __restrict__ part)
{
  __shared__ unsigned short Xs[128][72];   // [c2][n] transposed chunk
  const int sp = blockIdx.x;               // 0..SPLITS-1
  const int bh = blockIdx.y;               // 0..47
  const int b = bh / H_, h = bh % H_;
  const int t = threadIdx.x, lane = t & 63, w = t >> 6, wr = w >> 1, wc = w & 1;
  f32x4 acc[4][4] = {};
  const long rowbase = (long)b * N_ + (long)sp * NCHUNK;
  for (int st = 0; st < NCHUNK/64; ++st){
    __syncthreads();
    #pragma unroll
    for (int i = 0; i < 4; ++i){
      int idx = i*256 + t;
      int nl = idx >> 4, c8 = idx & 15;
      int col = (c8 < 8) ? (h*HD_ + c8*8) : (C_ + h*HD_ + (c8 - 8)*8);
      uint4 v = *(const uint4*)(qkv + (rowbase + st*64 + nl)*N1_ + col);
      const unsigned short* pv = (const unsigned short*)&v;
      #pragma unroll
      for (int j = 0; j < 8; ++j) Xs[c8*8 + j][nl] = pv[j];
    }
    __syncthreads();
    #pragma unroll
    for (int kk = 0; kk < 2; ++kk){
      const int koff = kk*32 + (lane >> 4) * 8;
      short8 a[4], bb[4];
      #pragma unroll
      for (int m = 0; m < 4; ++m)
        a[m] = *(const short8*)&Xs[wr*64 + m*16 + (lane & 15)][koff];
      #pragma unroll
      for (int n = 0; n < 4; ++n)
        bb[n] = *(const short8*)&Xs[wc*64 + n*16 + (lane & 15)][koff];
      #pragma unroll
      for (int m = 0; m < 4; ++m)
        #pragma unroll
        for (int n = 0; n < 4; ++n)
          acc[m][n] = __builtin_amdgcn_mfma_f32_16x16x32_bf16(a[m], bb[n], acc[m][n], 0, 0, 0);
    }
  }
  float* P = part + ((long)bh*SPLITS + sp) * 128 * 128;
  const int rl = (lane >> 4) * 4, cl = lane & 15;
  #pragma unroll
  for (int m = 0; m < 4; ++m)
    #pragma unroll
    for (int n = 0; n < 4; ++n)
      #pragma unroll
      for (int j = 0; j < 4; ++j)
        P[(wr*64 + m*16 + rl + j)*128 + wc*64 + n*16 + cl] = acc[m][n][j];
}

// ---------------- K3: reduce partials, norms, softmax -> attn ------------
__global__ __launch_bounds__(64)
void softmax_attn(const float* __restrict__ part, const float* __restrict__ temperature,
                  float* __restrict__ attn)
{
  const int bh = blockIdx.x, h = bh % H_;
  const int d = threadIdx.x;
  __shared__ float rnk[64];
  __shared__ float sl[64][65];
  const float* P = part + (long)bh * SPLITS * 16384;
  float nq2 = 0.f, nk2 = 0.f;
  for (int s = 0; s < SPLITS; ++s){
    nq2 += P[s*16384 + d*128 + d];
    nk2 += P[s*16384 + (64 + d)*128 + 64 + d];
  }
  const float rq = 1.0f / fmaxf(sqrtf(nq2), 1e-12f);
  rnk[d] = 1.0f / fmaxf(sqrtf(nk2), 1e-12f);
  __syncthreads();
  const float th = temperature[h];
  float mx = -1e30f;
  for (int e = 0; e < 64; ++e){
    float s = 0.f;
    for (int sp = 0; sp < SPLITS; ++sp) s += P[sp*16384 + d*128 + 64 + e];
    float l = th * s * rq * rnk[e];
    sl[d][e] = l;
    mx = fmaxf(mx, l);
  }
  float sum = 0.f;
  for (int e = 0; e < 64; ++e){ float ex = expf(sl[d][e] - mx); sl[d][e] = ex; sum += ex; }
  const float rs = 1.0f / sum;
  for (int e = 0; e < 64; ++e) attn[((long)bh*64 + d)*64 + e] = sl[d][e] * rs;
}

// ---------------- K4: WcombT[b][j][h*64+e] = sum_d attn[d][e]*Wproj[h*64+d][j]
__global__ __launch_bounds__(256)
void wcomb(const float* __restrict__ attn, const float* __restrict__ Wproj,
           unsigned short* __restrict__ WcT)
{
  const int bh = blockIdx.x;            // 0..47
  const int jt = blockIdx.y;            // 0..5
  const int b = bh / H_, h = bh % H_;
  __shared__ float sa[64][64];
  const int t = threadIdx.x;
  #pragma unroll
  for (int i = 0; i < 16; ++i){
    int idx = i*256 + t;
    sa[idx >> 6][idx & 63] = attn[(long)bh*4096 + idx];
  }
  __syncthreads();
  const int j  = jt*128 + (t & 127);
  const int e0 = (t >> 7) * 32;
  float acc[32] = {};
  for (int d = 0; d < 64; ++d){
    float wp = Wproj[(long)(h*HD_ + d)*C_ + j];
    #pragma unroll
    for (int i = 0; i < 32; ++i) acc[i] += sa[d][e0 + i] * wp;
  }
  #pragma unroll
  for (int i = 0; i < 32; ++i)
    WcT[((long)b*C_ + j)*C_ + h*HD_ + e0 + i] = f2b(acc[i]);
}

// ---------------- launch --------------------------------------------------
extern "C" void kernel_launch(void* const* d_in, const int* in_sizes, int n_in,
                              void* d_out, int out_size, void* d_ws, size_t ws_size,
                              hipStream_t stream)
{
  const float* x      = (const float*)d_in[0];
  const float* Wqkv   = (const float*)d_in[1];
  const float* bqkv   = (const float*)d_in[2];
  const float* temper = (const float*)d_in[3];
  const float* Wproj  = (const float*)d_in[4];
  const float* bproj  = (const float*)d_in[5];
  float* out = (float*)d_out;

  char* wp = (char*)d_ws;
  unsigned short* qkvB  = (unsigned short*)wp; wp += (size_t)MTOT * N1_ * 2;      // 151.0 MB
  unsigned short* WqkvT = (unsigned short*)wp; wp += (size_t)N1_ * C_ * 2;        // 3.5 MB
  unsigned short* WcT   = (unsigned short*)wp; wp += (size_t)B_ * C_ * C_ * 2;    // 4.7 MB
  float* part           = (float*)wp;          wp += (size_t)48 * SPLITS * 128 * 128 * 4; // 25.2 MB
  float* attn           = (float*)wp;          wp += (size_t)48 * 64 * 64 * 4;    // 0.79 MB

  // K0: WqkvT
  transpose_w<<<(N1_/32) * (C_/32), 256, 0, stream>>>(Wqkv, WqkvT, C_, N1_);
  // K1: qkvB = bf16(x @ Wqkv + bqkv); grid M-fastest for B-tile L2 reuse
  gemm_bt<1,1,0><<<(MTOT/128) * (N1_/128), 256, 0, stream>>>(
      (const void*)x, C_, 0, WqkvT, bqkv, (void*)qkvB, N1_, MTOT/128, C_);
  // K2: Gram partials
  gram_qk<<<dim3(SPLITS, 48), 256, 0, stream>>>(qkvB, part);
  // K3: softmax
  softmax_attn<<<48, 64, 0, stream>>>(part, temper, attn);
  // K4: combined weights
  wcomb<<<dim3(48, 6), 256, 0, stream>>>(attn, Wproj, WcT);
  // K5: out = V @ Wcomb[b] + bproj
  gemm_bt<0,0,1><<<(MTOT/128) * (C_/128), 256, 0, stream>>>(
      (const void*)qkvB, N1_, 2*C_, WcT, bproj, (void*)out, C_, MTOT/128, C_);
}

// Round 2
// 405.191 us; speedup vs baseline: 1.0506x; 1.0506x over previous
//
#include <hip/hip_runtime.h>
#include <hip/hip_bf16.h>

// CrossCovarianceAttn (XCiT channel attention), MI355X gfx950.
// Pipeline:
//   K0: transpose+cast Wqkv -> WqkvT bf16 [2304][768]
//   Kc: cast x fp32 -> xB bf16 (stored in d_out scratch, overwritten by K5)
//   K1: GEMM1 qkvB = bf16(xB @ Wqkv + bqkv)   [32768][2304] bf16  (m97-style)
//   K2: per (b,h,split): 128x128 Gram of [q|k] over n-chunk (MFMA), partials fp32
//   K3: reduce partials -> norms + softmax -> attn [48][64][64] fp32
//   K4: WcombT[b][j][h*64+e] = sum_d attn[b,h,d,e] * Wproj[h*64+d][j]  (bf16)
//   K5: GEMM2 out = V @ Wcomb[b] + bproj  (fp32 out)  (m97-style)

using short8 = __attribute__((ext_vector_type(8))) short;
using f32x4  = __attribute__((ext_vector_type(4))) float;

#define B_   4
#define N_   8192
#define C_   768
#define H_   12
#define HD_  64
#define N1_  (3*C_)      // 2304
#define MTOT (B_*N_)     // 32768
#define SPLITS 8
#define NCHUNK (N_/SPLITS)  // 1024

__device__ __forceinline__ unsigned short f2b(float f){
  union { float f; unsigned u; } v; v.f = f;
  unsigned u = v.u;
  u += 0x7fffu + ((u >> 16) & 1u);   // RNE
  return (unsigned short)(u >> 16);
}

// async global->LDS, 16B per lane; LDS dest = wave-uniform base + lane*16
#define GLOAD_LDS16(g, l) \
  __builtin_amdgcn_global_load_lds((const __attribute__((address_space(1))) void*)(g), \
                                   (__attribute__((address_space(3))) void*)(l), 16, 0, 0)

// ---------------- K0: Wqkv [768][2304] fp32 -> WqkvT [2304][768] bf16 ----
__global__ __launch_bounds__(256)
void transpose_w(const float* __restrict__ W, unsigned short* __restrict__ Wt,
                 int rows, int cols)
{
  __shared__ float tile[32][33];
  const int ctiles = cols / 32;
  const int bx = blockIdx.x % ctiles;   // col tile
  const int by = blockIdx.x / ctiles;   // row tile
  const int t = threadIdx.x;
  const int c = t & 31;
  #pragma unroll
  for (int i = 0; i < 4; ++i){
    int r = i*8 + (t >> 5);
    tile[r][c] = W[(long)(by*32 + r)*cols + bx*32 + c];
  }
  __syncthreads();
  #pragma unroll
  for (int i = 0; i < 4; ++i){
    int r = i*8 + (t >> 5);             // output row within tile (= original col)
    Wt[(long)(bx*32 + r)*rows + by*32 + c] = f2b(tile[c][r]);
  }
}

// ---------------- Kc: x fp32 -> bf16, 8 elems/thread, grid-stride ---------
__global__ __launch_bounds__(256)
void cvt_bf16(const float* __restrict__ in, unsigned short* __restrict__ out, long n8)
{
  long idx = (long)blockIdx.x*256 + threadIdx.x;
  const long stride = (long)gridDim.x*256;
  for (; idx < n8; idx += stride){
    const long i = idx*8;
    f32x4 v0 = *(const f32x4*)(in + i);
    f32x4 v1 = *(const f32x4*)(in + i + 4);
    uint4 o;
    o.x = (unsigned)f2b(v0[0]) | ((unsigned)f2b(v0[1]) << 16);
    o.y = (unsigned)f2b(v0[2]) | ((unsigned)f2b(v0[3]) << 16);
    o.z = (unsigned)f2b(v1[0]) | ((unsigned)f2b(v1[1]) << 16);
    o.w = (unsigned)f2b(v1[2]) | ((unsigned)f2b(v1[3]) << 16);
    *(uint4*)(out + i) = o;
  }
}

// ---------------- GEMM (bf16 MFMA, B pre-transposed [N][K], m97 structure)
// OUT_B16: bf16 out else fp32. B_PER_B: B matrix selected per batch.
// A bf16 [*, lda], offset a_off elems; K multiple of 64; M tile 128, N tile 128.
template<int OUT_B16, int B_PER_B>
__global__ __launch_bounds__(256)
void gemm_bt(const unsigned short* __restrict__ A, int lda, int a_off,
             const unsigned short* __restrict__ Bt,
             const float* __restrict__ bias,
             void* __restrict__ Outp, int ldo,
             int Mtiles, int K)
{
  __shared__ unsigned short As[128][64];   // linear: global_load_lds dest
  __shared__ unsigned short Bs[128][64];
  const int t = threadIdx.x;
  const int lane = t & 63, w = t >> 6, wr = w >> 1, wc = w & 1;
  // XCD-aware bijective swizzle (gridDim.x % 8 == 0 for all our launches)
  const int nwg = gridDim.x, cpx = nwg >> 3;
  const int bid = (int)blockIdx.x;
  const int swz = (bid & 7) * cpx + (bid >> 3);
  const int mt = swz % Mtiles;
  const int nt = swz / Mtiles;
  const long m0 = (long)mt * 128;
  const int  n0 = nt * 128;
  const unsigned short* B0 = Bt + (B_PER_B ? (long)(m0 / N_) * C_ * C_ : 0);
  const int arow = lane >> 3;          // row-within-segment this lane stages
  const int acol = (lane & 7) * 8;     // elem offset (16B) within row
  f32x4 acc[4][4] = {};
  const int ksteps = K / 64;
  for (int ks = 0; ks < ksteps; ++ks){
    const int k0 = ks * 64;
    __syncthreads();                   // previous MFMAs done reading LDS
    #pragma unroll
    for (int i = 0; i < 4; ++i){
      const int seg = i*4 + w;         // 16 segments of 8 rows (1024 B each)
      const int row = seg*8 + arow;
      GLOAD_LDS16(A  + (m0 + row)*(long)lda + a_off + k0 + acol, &As[seg*8][0]);
      GLOAD_LDS16(B0 + (long)(n0 + row)*K          + k0 + acol, &Bs[seg*8][0]);
    }
    __syncthreads();                   // compiler drains vmcnt(0) before barrier
    #pragma unroll
    for (int kk = 0; kk < 2; ++kk){
      const int koff = kk*32 + (lane >> 4) * 8;
      short8 a[4], bb[4];
      #pragma unroll
      for (int m = 0; m < 4; ++m)
        a[m] = *(const short8*)&As[wr*64 + m*16 + (lane & 15)][koff];
      #pragma unroll
      for (int n = 0; n < 4; ++n)
        bb[n] = *(const short8*)&Bs[wc*64 + n*16 + (lane & 15)][koff];
      #pragma unroll
      for (int m = 0; m < 4; ++m)
        #pragma unroll
        for (int n = 0; n < 4; ++n)
          acc[m][n] = __builtin_amdgcn_mfma_f32_16x16x32_bf16(a[m], bb[n], acc[m][n], 0, 0, 0);
    }
  }
  const int rl = (lane >> 4) * 4, cl = lane & 15;
  #pragma unroll
  for (int m = 0; m < 4; ++m){
    const long gr = m0 + wr*64 + m*16 + rl;
    #pragma unroll
    for (int n = 0; n < 4; ++n){
      const int gc = n0 + wc*64 + n*16 + cl;
      const float bv = bias[gc];
      #pragma unroll
      for (int j = 0; j < 4; ++j){
        float v = acc[m][n][j] + bv;
        if (OUT_B16) ((unsigned short*)Outp)[(gr + j)*(long)ldo + gc] = f2b(v);
        else         ((float*)Outp)[(gr + j)*(long)ldo + gc] = v;
      }
    }
  }
}

// ---------------- K2: per (b,h,split) 128x128 Gram of stacked [q|k] ------
__global__ __launch_bounds__(256)
void gram_qk(const unsigned short* __restrict__ qkv, float* __restrict__ part)
{
  __shared__ unsigned short Xs[128][72];   // [c2][n] transposed chunk
  const int sp = blockIdx.x;               // 0..SPLITS-1
  const int bh = blockIdx.y;               // 0..47
  const int b = bh / H_, h = bh % H_;
  const int t = threadIdx.x, lane = t & 63, w = t >> 6, wr = w >> 1, wc = w & 1;
  f32x4 acc[4][4] = {};
  const long rowbase = (long)b * N_ + (long)sp * NCHUNK;
  for (int st = 0; st < NCHUNK/64; ++st){
    __syncthreads();
    #pragma unroll
    for (int i = 0; i < 4; ++i){
      int idx = i*256 + t;
      int nl = idx >> 4, c8 = idx & 15;
      int col = (c8 < 8) ? (h*HD_ + c8*8) : (C_ + h*HD_ + (c8 - 8)*8);
      uint4 v = *(const uint4*)(qkv + (rowbase + st*64 + nl)*N1_ + col);
      const unsigned short* pv = (const unsigned short*)&v;
      #pragma unroll
      for (int j = 0; j < 8; ++j) Xs[c8*8 + j][nl] = pv[j];
    }
    __syncthreads();
    #pragma unroll
    for (int kk = 0; kk < 2; ++kk){
      const int koff = kk*32 + (lane >> 4) * 8;
      short8 a[4], bb[4];
      #pragma unroll
      for (int m = 0; m < 4; ++m)
        a[m] = *(const short8*)&Xs[wr*64 + m*16 + (lane & 15)][koff];
      #pragma unroll
      for (int n = 0; n < 4; ++n)
        bb[n] = *(const short8*)&Xs[wc*64 + n*16 + (lane & 15)][koff];
      #pragma unroll
      for (int m = 0; m < 4; ++m)
        #pragma unroll
        for (int n = 0; n < 4; ++n)
          acc[m][n] = __builtin_amdgcn_mfma_f32_16x16x32_bf16(a[m], bb[n], acc[m][n], 0, 0, 0);
    }
  }
  float* P = part + ((long)bh*SPLITS + sp) * 128 * 128;
  const int rl = (lane >> 4) * 4, cl = lane & 15;
  #pragma unroll
  for (int m = 0; m < 4; ++m)
    #pragma unroll
    for (int n = 0; n < 4; ++n)
      #pragma unroll
      for (int j = 0; j < 4; ++j)
        P[(wr*64 + m*16 + rl + j)*128 + wc*64 + n*16 + cl] = acc[m][n][j];
}

// ---------------- K3: reduce partials, norms, softmax -> attn ------------
__global__ __launch_bounds__(64)
void softmax_attn(const float* __restrict__ part, const float* __restrict__ temperature,
                  float* __restrict__ attn)
{
  const int bh = blockIdx.x, h = bh % H_;
  const int d = threadIdx.x;
  __shared__ float rnk[64];
  __shared__ float sl[64][65];
  const float* P = part + (long)bh * SPLITS * 16384;
  float nq2 = 0.f, nk2 = 0.f;
  for (int s = 0; s < SPLITS; ++s){
    nq2 += P[s*16384 + d*128 + d];
    nk2 += P[s*16384 + (64 + d)*128 + 64 + d];
  }
  const float rq = 1.0f / fmaxf(sqrtf(nq2), 1e-12f);
  rnk[d] = 1.0f / fmaxf(sqrtf(nk2), 1e-12f);
  __syncthreads();
  const float th = temperature[h];
  float mx = -1e30f;
  for (int e = 0; e < 64; ++e){
    float s = 0.f;
    for (int sp = 0; sp < SPLITS; ++sp) s += P[sp*16384 + d*128 + 64 + e];
    float l = th * s * rq * rnk[e];
    sl[d][e] = l;
    mx = fmaxf(mx, l);
  }
  float sum = 0.f;
  for (int e = 0; e < 64; ++e){ float ex = expf(sl[d][e] - mx); sl[d][e] = ex; sum += ex; }
  const float rs = 1.0f / sum;
  for (int e = 0; e < 64; ++e) attn[((long)bh*64 + d)*64 + e] = sl[d][e] * rs;
}

// ---------------- K4: WcombT[b][j][h*64+e] = sum_d attn[d][e]*Wproj[h*64+d][j]
__global__ __launch_bounds__(256)
void wcomb(const float* __restrict__ attn, const float* __restrict__ Wproj,
           unsigned short* __restrict__ WcT)
{
  const int bh = blockIdx.x;            // 0..47
  const int jt = blockIdx.y;            // 0..5
  const int b = bh / H_, h = bh % H_;
  __shared__ float sa[64][64];
  const int t = threadIdx.x;
  #pragma unroll
  for (int i = 0; i < 16; ++i){
    int idx = i*256 + t;
    sa[idx >> 6][idx & 63] = attn[(long)bh*4096 + idx];
  }
  __syncthreads();
  const int j  = jt*128 + (t & 127);
  const int e0 = (t >> 7) * 32;
  float acc[32] = {};
  for (int d = 0; d < 64; ++d){
    float wp = Wproj[(long)(h*HD_ + d)*C_ + j];
    #pragma unroll
    for (int i = 0; i < 32; ++i) acc[i] += sa[d][e0 + i] * wp;
  }
  #pragma unroll
  for (int i = 0; i < 32; ++i)
    WcT[((long)b*C_ + j)*C_ + h*HD_ + e0 + i] = f2b(acc[i]);
}

// ---------------- launch --------------------------------------------------
extern "C" void kernel_launch(void* const* d_in, const int* in_sizes, int n_in,
                              void* d_out, int out_size, void* d_ws, size_t ws_size,
                              hipStream_t stream)
{
  const float* x      = (const float*)d_in[0];
  const float* Wqkv   = (const float*)d_in[1];
  const float* bqkv   = (const float*)d_in[2];
  const float* temper = (const float*)d_in[3];
  const float* Wproj  = (const float*)d_in[4];
  const float* bproj  = (const float*)d_in[5];
  float* out = (float*)d_out;

  char* wp = (char*)d_ws;
  unsigned short* qkvB  = (unsigned short*)wp; wp += (size_t)MTOT * N1_ * 2;      // 151.0 MB
  unsigned short* WqkvT = (unsigned short*)wp; wp += (size_t)N1_ * C_ * 2;        // 3.5 MB
  unsigned short* WcT   = (unsigned short*)wp; wp += (size_t)B_ * C_ * C_ * 2;    // 4.7 MB
  float* part           = (float*)wp;          wp += (size_t)48 * SPLITS * 128 * 128 * 4; // 25.2 MB
  float* attn           = (float*)wp;          wp += (size_t)48 * 64 * 64 * 4;    // 0.79 MB
  // xB (48 MB) lives in d_out (96 MB fp32): consumed by K1, then K5 fully
  // overwrites d_out. Deterministic: same sequence every call.
  unsigned short* xB = (unsigned short*)d_out;

  // K0: WqkvT
  transpose_w<<<(N1_/32) * (C_/32), 256, 0, stream>>>(Wqkv, WqkvT, C_, N1_);
  // Kc: xB = bf16(x)
  cvt_bf16<<<2048, 256, 0, stream>>>(x, xB, (long)MTOT * C_ / 8);
  // K1: qkvB = bf16(xB @ Wqkv + bqkv); grid M-fastest, XCD-swizzled in-kernel
  gemm_bt<1,0><<<(MTOT/128) * (N1_/128), 256, 0, stream>>>(
      xB, C_, 0, WqkvT, bqkv, (void*)qkvB, N1_, MTOT/128, C_);
  // K2: Gram partials
  gram_qk<<<dim3(SPLITS, 48), 256, 0, stream>>>(qkvB, part);
  // K3: softmax
  softmax_attn<<<48, 64, 0, stream>>>(part, temper, attn);
  // K4: combined weights
  wcomb<<<dim3(48, 6), 256, 0, stream>>>(attn, Wproj, WcT);
  // K5: out = V @ Wcomb[b] + bproj
  gemm_bt<0,1><<<(MTOT/128) * (C_/128), 256, 0, stream>>>(
      qkvB, N1_, 2*C_, WcT, bproj, (void*)out, C_, MTOT/128, C_);
}